// Round 8
// baseline (70.738 us; speedup 1.0000x reference)
//
#include <hip/hip_runtime.h>

namespace {
constexpr int DIM = 16;
constexpr int H = 96, W = 96, CH = 16;
constexpr int OH = 95, OW = 95;
constexpr int NF = 8, NW = 24;
constexpr int NPIX = 8 * OH * OW;             // 72200
constexpr int PPB = 256;                      // patches per block
constexpr int NBLK = (NPIX + PPB - 1) / PPB;  // 283

// LDS float offsets (single pool, 43 KB)
constexpr int OFF_CW = 0;                 // 192 cos(w/2)
constexpr int OFF_SW = 192;               // 192 sin(w/2)
constexpr int OFF_PSI = 384;              // 256*17
constexpr int OFF_M = 384 + 4352;         // 8*256
constexpr int OFF_V = 384 + 4352 + 2048;  // Vr 8*264
constexpr int VI_REL = 8 * 264;           // Vi after Vr
constexpr int OFF_OS = OFF_V;             // os (256*9) aliases V after bar3
constexpr int LDS_FLOATS = OFF_V + 2 * 8 * 264;  // 11008 floats
}

__global__ __launch_bounds__(512, 4)
void qconv_one(const float* __restrict__ x, const float* __restrict__ wts,
               float* __restrict__ out) {
  __shared__ float sm[LDS_FLOATS];
  const int tid = threadIdx.x;
  const int pbase = blockIdx.x * PPB;

  // ---- concurrent phase: psi (threads 256-511) | weight sincos (128-255) ----
  if (tid >= 256) {
    int n = pbase + (tid - 256);
    if (n >= NPIX) n = NPIX - 1;
    const int b = n / (OH * OW);
    const int rem = n - b * (OH * OW);
    const int oi = rem / OW;
    const int oj = rem - oi * OW;

    const float* base = x + (((b * H) + oi) * W + oj) * CH;
    float ss = 0.f;
    float4 f0 = make_float4(0.f, 0.f, 0.f, 0.f);
#pragma unroll
    for (int fi = 0; fi < 2; ++fi) {
      const float4* row = reinterpret_cast<const float4*>(base + fi * W * CH);
#pragma unroll
      for (int k = 0; k < 8; ++k) {
        const float4 v = row[k];
        if (fi == 0 && k == 0) f0 = v;
        ss = fmaf(v.x, v.x, ss); ss = fmaf(v.y, v.y, ss);
        ss = fmaf(v.z, v.z, ss); ss = fmaf(v.w, v.w, ss);
      }
    }
    const float inv = rsqrtf(fmaxf(ss, 1e-12f));
    float cq[4], sq[4];
    __sincosf(f0.x * inv * 0.5f, &sq[0], &cq[0]);
    __sincosf(f0.y * inv * 0.5f, &sq[1], &cq[1]);
    __sincosf(f0.z * inv * 0.5f, &sq[2], &cq[2]);
    __sincosf(f0.w * inv * 0.5f, &sq[3], &cq[3]);
    float* dst = sm + OFF_PSI + (tid - 256) * 17;
#pragma unroll
    for (int i = 0; i < DIM; ++i) {
      dst[i] = ((i & 8) ? sq[0] : cq[0]) * ((i & 4) ? sq[1] : cq[1]) *
               ((i & 2) ? sq[2] : cq[2]) * ((i & 1) ? sq[3] : cq[3]);
    }
  } else if (tid >= 128) {
    const int i0 = tid - 128;
    float s, c;
    __sincosf(wts[i0] * 0.5f, &s, &c);
    sm[OFF_CW + i0] = c;
    sm[OFF_SW + i0] = s;
    if (i0 < 64) {
      const int i1 = i0 + 128;
      __sincosf(wts[i1] * 0.5f, &s, &c);
      sm[OFF_CW + i1] = c;
      sm[OFF_SW + i1] = s;
    }
  }
  __syncthreads();  // bar1: cw/sw + psis ready

  // ---- circuit: threads 0-127, (f, col) -> column of U, store perm-baked ----
  if (tid < 128) {
    const int f = tid >> 4;
    const int col = tid & 15;
    const float* fc = sm + OFF_CW + f * NW;
    const float* fs = sm + OFF_SW + f * NW;
    float ar[DIM], ai[DIM];
#pragma unroll
    for (int i = 0; i < DIM; ++i) { ar[i] = (i == col) ? 1.f : 0.f; ai[i] = 0.f; }
#pragma unroll
    for (int layer = 0; layer < 2; ++layer) {
      const int wb = layer * 12;
#pragma unroll
      for (int q = 0; q < 4; ++q) {
        const int m = 8 >> q;
        {  // RX
          const float c = fc[wb + q * 3], s = fs[wb + q * 3];
#pragma unroll
          for (int i = 0; i < DIM; ++i) {
            if (i & m) continue;
            const int j = i | m;
            const float a0r = ar[i], a0i = ai[i], a1r = ar[j], a1i = ai[j];
            ar[i] = fmaf(c, a0r,  s * a1i);
            ai[i] = fmaf(c, a0i, -s * a1r);
            ar[j] = fmaf(c, a1r,  s * a0i);
            ai[j] = fmaf(c, a1i, -s * a0r);
          }
        }
        {  // RY
          const float c = fc[wb + q * 3 + 1], s = fs[wb + q * 3 + 1];
#pragma unroll
          for (int i = 0; i < DIM; ++i) {
            if (i & m) continue;
            const int j = i | m;
            const float a0r = ar[i], a0i = ai[i], a1r = ar[j], a1i = ai[j];
            ar[i] = fmaf(c, a0r, -s * a1r);
            ai[i] = fmaf(c, a0i, -s * a1i);
            ar[j] = fmaf(s, a0r,  c * a1r);
            ai[j] = fmaf(s, a0i,  c * a1i);
          }
        }
        {  // RZ
          const float c = fc[wb + q * 3 + 2], s = fs[wb + q * 3 + 2];
#pragma unroll
          for (int i = 0; i < DIM; ++i) {
            const float r = ar[i], im = ai[i];
            if (i & m) { ar[i] = fmaf(c, r, -s * im); ai[i] = fmaf(c, im,  s * r); }
            else       { ar[i] = fmaf(c, r,  s * im); ai[i] = fmaf(c, im, -s * r); }
          }
        }
      }
      {  // CRY(ctrl bit8, tgt bit4)
        const float c = fc[wb + 0], s = fs[wb + 0];
#pragma unroll
        for (int i = 0; i < DIM; ++i) {
          if (!(i & 8) || (i & 4)) continue;
          const int j = i | 4;
          const float a0r = ar[i], a0i = ai[i], a1r = ar[j], a1i = ai[j];
          ar[i] = fmaf(c, a0r, -s * a1r);
          ai[i] = fmaf(c, a0i, -s * a1i);
          ar[j] = fmaf(s, a0r,  c * a1r);
          ai[j] = fmaf(s, a0i,  c * a1i);
        }
      }
      {  // CRY(ctrl bit2, tgt bit1)
        const float c = fc[wb + 2], s = fs[wb + 2];
#pragma unroll
        for (int i = 0; i < DIM; ++i) {
          if (!(i & 2) || (i & 1)) continue;
          const int j = i | 1;
          const float a0r = ar[i], a0i = ai[i], a1r = ar[j], a1i = ai[j];
          ar[i] = fmaf(c, a0r, -s * a1r);
          ai[i] = fmaf(c, a0i, -s * a1i);
          ar[j] = fmaf(s, a0r,  c * a1r);
          ai[j] = fmaf(s, a0i,  c * a1i);
        }
      }
    }
    // store column col at slot jc = invperm(col): V[i][jc] = U[i][col]
    const int jc = col ^ (col >> 1);
    float* vr = sm + OFF_V + f * 264;
#pragma unroll
    for (int i = 0; i < DIM; ++i) {
      vr[i * 16 + jc] = ar[i];
      vr[VI_REL + i * 16 + jc] = ai[i];
    }
  }
  __syncthreads();  // bar2: V ready

  // ---- M-assembly: threads 0-127, 4x4 tile each; skip z==0 rows ----
  if (tid < 128) {
    const int f = tid >> 4;
    const int tt = tid & 15;
    const int k0 = (tt >> 2) << 2;
    const int j0 = (tt & 3) << 2;
    const float* vr = sm + OFF_V + f * 264;
    float acc[4][4];
#pragma unroll
    for (int a = 0; a < 4; ++a)
#pragma unroll
      for (int b2 = 0; b2 < 4; ++b2) acc[a][b2] = 0.f;

#pragma unroll
    for (int i = 0; i < DIM; ++i) {
      constexpr float ZT[16] = {1.f, .5f, .5f, 0.f, .5f, 0.f, 0.f, -.5f,
                                .5f, 0.f, 0.f, -.5f, 0.f, -.5f, -.5f, -1.f};
      const float z = ZT[i];
      if (z == 0.f) continue;  // compile-time pruned
      const float4 kr = *reinterpret_cast<const float4*>(vr + i * 16 + k0);
      const float4 jr = *reinterpret_cast<const float4*>(vr + i * 16 + j0);
      const float4 ki = *reinterpret_cast<const float4*>(vr + VI_REL + i * 16 + k0);
      const float4 ji = *reinterpret_cast<const float4*>(vr + VI_REL + i * 16 + j0);
      const float zk[4] = {z * kr.x, z * kr.y, z * kr.z, z * kr.w};
      const float zi[4] = {z * ki.x, z * ki.y, z * ki.z, z * ki.w};
      const float jrv[4] = {jr.x, jr.y, jr.z, jr.w};
      const float jiv[4] = {ji.x, ji.y, ji.z, ji.w};
#pragma unroll
      for (int a = 0; a < 4; ++a)
#pragma unroll
        for (int b2 = 0; b2 < 4; ++b2) {
          acc[a][b2] = fmaf(zk[a], jrv[b2], acc[a][b2]);
          acc[a][b2] = fmaf(zi[a], jiv[b2], acc[a][b2]);
        }
    }
    float* mrow = sm + OFF_M + f * 256;
#pragma unroll
    for (int a = 0; a < 4; ++a) {
      *reinterpret_cast<float4*>(mrow + (k0 + a) * 16 + j0) =
          make_float4(acc[a][0], acc[a][1], acc[a][2], acc[a][3]);
    }
  }
  __syncthreads();  // bar3: M ready, V dead (os may alias)

  // ---- phase B: wave = filter; 4 patches/lane; s_p = psi^T M psi ----
  {
    const int lane = tid & 63;
    const int f = __builtin_amdgcn_readfirstlane(tid >> 6);
    const float* M = sm + OFF_M + f * 256;

    float pa[4][16];
#pragma unroll
    for (int p = 0; p < 4; ++p) {
      const float* ps = sm + OFF_PSI + (p * 64 + lane) * 17;
#pragma unroll
      for (int k = 0; k < 16; ++k) pa[p][k] = ps[k];
    }

    float s[4] = {0.f, 0.f, 0.f, 0.f};
#pragma unroll
    for (int k = 0; k < 16; ++k) {
      const float4 m0 = *reinterpret_cast<const float4*>(M + k * 16 + 0);
      const float4 m1 = *reinterpret_cast<const float4*>(M + k * 16 + 4);
      const float4 m2 = *reinterpret_cast<const float4*>(M + k * 16 + 8);
      const float4 m3 = *reinterpret_cast<const float4*>(M + k * 16 + 12);
#pragma unroll
      for (int p = 0; p < 4; ++p) {
        float rlo = m0.x * pa[p][0];
        rlo = fmaf(m0.y, pa[p][1], rlo);
        rlo = fmaf(m0.z, pa[p][2], rlo);
        rlo = fmaf(m0.w, pa[p][3], rlo);
        rlo = fmaf(m1.x, pa[p][4], rlo);
        rlo = fmaf(m1.y, pa[p][5], rlo);
        rlo = fmaf(m1.z, pa[p][6], rlo);
        rlo = fmaf(m1.w, pa[p][7], rlo);
        float rhi = m2.x * pa[p][8];
        rhi = fmaf(m2.y, pa[p][9], rhi);
        rhi = fmaf(m2.z, pa[p][10], rhi);
        rhi = fmaf(m2.w, pa[p][11], rhi);
        rhi = fmaf(m3.x, pa[p][12], rhi);
        rhi = fmaf(m3.y, pa[p][13], rhi);
        rhi = fmaf(m3.z, pa[p][14], rhi);
        rhi = fmaf(m3.w, pa[p][15], rhi);
        s[p] = fmaf(pa[p][k], rlo + rhi, s[p]);
      }
    }
#pragma unroll
    for (int p = 0; p < 4; ++p) sm[OFF_OS + (p * 64 + lane) * 9 + f] = s[p];
  }
  __syncthreads();  // bar4

  // ---- coalesced store: 2048 floats, 512 threads x float4 ----
  {
    const int pp = tid >> 1;
    const int e = (tid & 1) * 4;
    if (tid * 4 < (NPIX - pbase) * 8) {
      const float* o = sm + OFF_OS + pp * 9 + e;
      *reinterpret_cast<float4*>(out + (long)pbase * 8 + tid * 4) =
          make_float4(o[0], o[1], o[2], o[3]);
    }
  }
}

extern "C" void kernel_launch(void* const* d_in, const int* in_sizes, int n_in,
                              void* d_out, int out_size, void* d_ws, size_t ws_size,
                              hipStream_t stream) {
  const float* x = (const float*)d_in[0];
  const float* w = (const float*)d_in[1];
  float* out = (float*)d_out;
  qconv_one<<<dim3(NBLK), dim3(512), 0, stream>>>(x, w, out);
}